// Round 3
// baseline (628.339 us; speedup 1.0000x reference)
//
#include <hip/hip_runtime.h>

// SGCN fused: out[n,f,t,w] = sum_v (sum_c x[n,c,t,v]*W[c,f] + b[f]) * a[n,t,v,w]
// Shapes: x[128,256,64,32], a[128,64,32,32], W[256,256], b[256]
// d_out = out (67,108,864 f32) ++ a (8,388,608 f32)

#define NN 128
#define CC 256
#define TT 64
#define VV 32
#define FF 256

__global__ __launch_bounds__(256) void sgcn_fused_kernel(
    const float* __restrict__ x, const float* __restrict__ a,
    const float* __restrict__ W, const float* __restrict__ b,
    float* __restrict__ out, float* __restrict__ out_a)
{
    __shared__ float x_lds[CC][VV];   // 32 KB: x[n, :, t, :]
    __shared__ float a_lds[VV][VV];   // 4 KB:  a[n, t, :, :]

    const int tid = threadIdx.x;
    const int nt  = blockIdx.x;          // n*TT + t
    const int n   = nt >> 6;             // / 64
    const int t   = nt & 63;             // % 64

    // ---- stage x[n, :, t, :] into LDS (8192 floats, 32 per thread as 8x float4)
    const float* xb = x + (size_t)n * CC * TT * VV + (size_t)t * VV;
    #pragma unroll
    for (int k = 0; k < 8; ++k) {
        int e = tid * 4 + k * 1024;      // element index in [0, 8192)
        int c = e >> 5, v = e & 31;
        float4 val = *reinterpret_cast<const float4*>(xb + (size_t)c * (TT * VV) + v);
        *reinterpret_cast<float4*>(&x_lds[c][v]) = val;
    }

    // ---- stage a[n,t] into LDS and mirror it to the output tuple tail
    {
        const float* ab = a + (size_t)nt * (VV * VV);
        float4 av = *reinterpret_cast<const float4*>(ab + tid * 4);
        *reinterpret_cast<float4*>(&a_lds[0][0] + tid * 4) = av;
        *reinterpret_cast<float4*>(out_a + (size_t)nt * (VV * VV) + tid * 4) = av;
    }
    __syncthreads();

    const int f = tid;

    // ---- phase 1: h[f, v] = sum_c x[c,v] * W[c,f]   (W reads coalesced, L2-resident)
    float h[VV];
    #pragma unroll
    for (int v = 0; v < VV; ++v) h[v] = 0.0f;

    #pragma unroll 4
    for (int c = 0; c < CC; ++c) {
        float wv = W[c * FF + f];
        #pragma unroll
        for (int v = 0; v < VV; ++v)
            h[v] = fmaf(x_lds[c][v], wv, h[v]);
    }

    const float bias = b[f];
    #pragma unroll
    for (int v = 0; v < VV; ++v) h[v] += bias;

    // ---- phase 2: out[f, w] = sum_v h[v] * a[v, w]  (a reads are LDS broadcasts)
    float o[VV];
    #pragma unroll
    for (int w = 0; w < VV; ++w) o[w] = 0.0f;

    #pragma unroll
    for (int v = 0; v < VV; ++v) {
        float hv = h[v];
        #pragma unroll
        for (int w = 0; w < VV; ++w)
            o[w] = fmaf(hv, a_lds[v][w], o[w]);
    }

    // ---- store out[n, f, t, :] (32 contiguous floats)
    float* ob = out + (((size_t)n * FF + f) * TT + t) * VV;
    #pragma unroll
    for (int w = 0; w < VV; w += 4)
        *reinterpret_cast<float4*>(ob + w) = make_float4(o[w], o[w+1], o[w+2], o[w+3]);
}

extern "C" void kernel_launch(void* const* d_in, const int* in_sizes, int n_in,
                              void* d_out, int out_size, void* d_ws, size_t ws_size,
                              hipStream_t stream) {
    const float* x = (const float*)d_in[0];
    const float* a = (const float*)d_in[1];
    const float* W = (const float*)d_in[2];
    const float* b = (const float*)d_in[3];

    float* out   = (float*)d_out;
    float* out_a = out + (size_t)NN * FF * TT * VV;   // tuple tail: a pass-through

    dim3 grid(NN * TT);
    dim3 block(256);
    sgcn_fused_kernel<<<grid, block, 0, stream>>>(x, a, W, b, out, out_a);
}

// Round 4
// 243.680 us; speedup vs baseline: 2.5785x; 2.5785x over previous
//
#include <hip/hip_runtime.h>

// SGCN fused, MFMA version.
// out[n,f,t,w] = sum_c W[c,f] * g[n,c,t,w] + b[f] * s[n,t,w]
//   where g[n,c,t,w] = sum_v x[n,c,t,v] * a[n,t,v,w],  s = sum_v a[n,t,v,w]
// Shapes: x[128,256,64,32] f32, a[128,64,32,32] f32, W[256,256] f32, b[256] f32
// d_out = out (67,108,864 f32) ++ a (8,388,608 f32)
// d_ws  = Wt f16 [f][c] (131072 bytes)

#define NN 128
#define CC 256
#define TT 64
#define VV 32
#define FF 256

typedef _Float16 half8 __attribute__((ext_vector_type(8)));
typedef _Float16 half4 __attribute__((ext_vector_type(4)));
typedef float floatx4 __attribute__((ext_vector_type(4)));

#define AT_LD 40    // a_t row stride in f16 (32 + 8 pad) -> 20 words: 2-way banks
#define G_LD 280    // g_lds row stride in f16 (256 + 24 pad) -> 140 words == 12 mod 32: 2-way

// ---- prep: Wt[f][c] = (f16) W[c][f]   (runs once per launch, ~128 KB)
__global__ __launch_bounds__(256) void wt_prep_kernel(const float* __restrict__ W,
                                                      _Float16* __restrict__ Wt) {
    const int c = blockIdx.x;
    const int f = threadIdx.x;
    Wt[f * CC + c] = (_Float16)W[c * FF + f];
}

__global__ __launch_bounds__(256) void sgcn_mfma_kernel(
    const float* __restrict__ x, const float* __restrict__ a,
    const _Float16* __restrict__ Wt, const float* __restrict__ b,
    float* __restrict__ out, float* __restrict__ out_a)
{
    __shared__ _Float16 a_t[VV][AT_LD];    // a^T  [w][v]
    __shared__ _Float16 g_lds[VV][G_LD];   // g^T  [w][c]
    __shared__ float    s_lds[VV];         // column sums of a

    const int tid  = threadIdx.x;
    const int lane = tid & 63;
    const int wv   = tid >> 6;       // wave 0..3
    const int nt   = blockIdx.x;
    const int n    = nt >> 6;
    const int t    = nt & 63;
    const int l15  = lane & 15;
    const int lg   = lane >> 4;      // 0..3

    // ---- phase 0: load a[n,t] (f32), mirror to out tail, transpose into a_t (f16)
    {
        const float* ab = a + (size_t)nt * (VV * VV);
        float4 av = *reinterpret_cast<const float4*>(ab + tid * 4);
        *reinterpret_cast<float4*>(out_a + (size_t)nt * (VV * VV) + tid * 4) = av;
        const int e  = tid * 4;
        const int v  = e >> 5;       // row of a
        const int w0 = e & 31;       // 4 consecutive w
        a_t[w0 + 0][v] = (_Float16)av.x;
        a_t[w0 + 1][v] = (_Float16)av.y;
        a_t[w0 + 2][v] = (_Float16)av.z;
        a_t[w0 + 3][v] = (_Float16)av.w;
    }
    __syncthreads();

    // ---- s[w] = sum_v a[v][w] (bias term); threads 0..31 while others proceed
    if (tid < 32) {
        float ssum = 0.0f;
        #pragma unroll
        for (int v = 0; v < VV; ++v) ssum += (float)a_t[tid][v];
        s_lds[tid] = ssum;
    }

    // B-frags of a for GEMM-A: lane -> col w = 16*wt + l15, k = v = 8*lg + j
    half8 bA[2];
    #pragma unroll
    for (int wt = 0; wt < 2; ++wt)
        bA[wt] = *reinterpret_cast<const half8*>(&a_t[16 * wt + l15][8 * lg]);

    // ---- phase 1: GEMM-A  g[c,w] = sum_v x[c,v]*a[v,w]; wave wv owns c-tiles 4wv..4wv+3
    #pragma unroll
    for (int ci = 0; ci < 4; ++ci) {
        const int ct = wv * 4 + ci;
        const int c  = ct * 16 + l15;
        // A-frag directly from global: x[n, c, t, 8*lg .. 8*lg+7]
        const float* xp = x + (((size_t)n * CC + c) * TT + t) * VV + 8 * lg;
        float4 x0 = *reinterpret_cast<const float4*>(xp);
        float4 x1 = *reinterpret_cast<const float4*>(xp + 4);
        half8 af;
        af[0] = (_Float16)x0.x; af[1] = (_Float16)x0.y;
        af[2] = (_Float16)x0.z; af[3] = (_Float16)x0.w;
        af[4] = (_Float16)x1.x; af[5] = (_Float16)x1.y;
        af[6] = (_Float16)x1.z; af[7] = (_Float16)x1.w;
        #pragma unroll
        for (int wt = 0; wt < 2; ++wt) {
            floatx4 acc = {0.f, 0.f, 0.f, 0.f};
            acc = __builtin_amdgcn_mfma_f32_16x16x32_f16(af, bA[wt], acc, 0, 0, 0);
            // C-layout: lane holds rows c = ct*16 + 4*lg + r (r=0..3), col w = 16*wt + l15
            // -> 4 consecutive c at fixed w: one 8-byte write into g^T[w][c]
            half4 gh;
            gh[0] = (_Float16)acc[0]; gh[1] = (_Float16)acc[1];
            gh[2] = (_Float16)acc[2]; gh[3] = (_Float16)acc[3];
            *reinterpret_cast<half4*>(&g_lds[16 * wt + l15][ct * 16 + 4 * lg]) = gh;
        }
    }
    __syncthreads();

    // ---- phase 2: GEMM-B  out[f,w] = sum_c Wt[f][c]*g[c,w]; wave wv owns f-tiles 4wv..4wv+3
    floatx4 acc[4][2];
    #pragma unroll
    for (int fi = 0; fi < 4; ++fi)
        #pragma unroll
        for (int wt = 0; wt < 2; ++wt)
            acc[fi][wt] = (floatx4){0.f, 0.f, 0.f, 0.f};

    #pragma unroll
    for (int ks = 0; ks < 8; ++ks) {
        half8 bB[2];
        #pragma unroll
        for (int wt = 0; wt < 2; ++wt)
            bB[wt] = *reinterpret_cast<const half8*>(&g_lds[16 * wt + l15][32 * ks + 8 * lg]);
        #pragma unroll
        for (int fi = 0; fi < 4; ++fi) {
            const int ft = wv * 4 + fi;
            const _Float16* wp = Wt + (size_t)(16 * ft + l15) * CC + 32 * ks + 8 * lg;
            half8 afr = *reinterpret_cast<const half8*>(wp);
            acc[fi][0] = __builtin_amdgcn_mfma_f32_16x16x32_f16(afr, bB[0], acc[fi][0], 0, 0, 0);
            acc[fi][1] = __builtin_amdgcn_mfma_f32_16x16x32_f16(afr, bB[1], acc[fi][1], 0, 0, 0);
        }
    }

    // ---- epilogue: out[n,f,t,w] = acc + b[f]*s[w]
    #pragma unroll
    for (int fi = 0; fi < 4; ++fi) {
        const int ft = wv * 4 + fi;
        const int f0 = 16 * ft + 4 * lg;
        #pragma unroll
        for (int wt = 0; wt < 2; ++wt) {
            const int w  = 16 * wt + l15;
            const float sw = s_lds[w];
            #pragma unroll
            for (int r = 0; r < 4; ++r) {
                const int f = f0 + r;
                const float val = acc[fi][wt][r] + b[f] * sw;
                out[(((size_t)n * FF + f) * TT + t) * VV + w] = val;
            }
        }
    }
}

// ---- fallback (verified round-3 kernel, absmax 0): used only if ws too small
__global__ __launch_bounds__(256) void sgcn_fused_kernel(
    const float* __restrict__ x, const float* __restrict__ a,
    const float* __restrict__ W, const float* __restrict__ b,
    float* __restrict__ out, float* __restrict__ out_a)
{
    __shared__ float x_lds[CC][VV];
    __shared__ float a_lds[VV][VV];

    const int tid = threadIdx.x;
    const int nt  = blockIdx.x;
    const int n   = nt >> 6;
    const int t   = nt & 63;

    const float* xb = x + (size_t)n * CC * TT * VV + (size_t)t * VV;
    #pragma unroll
    for (int k = 0; k < 8; ++k) {
        int e = tid * 4 + k * 1024;
        int c = e >> 5, v = e & 31;
        float4 val = *reinterpret_cast<const float4*>(xb + (size_t)c * (TT * VV) + v);
        *reinterpret_cast<float4*>(&x_lds[c][v]) = val;
    }
    {
        const float* ab = a + (size_t)nt * (VV * VV);
        float4 av = *reinterpret_cast<const float4*>(ab + tid * 4);
        *reinterpret_cast<float4*>(&a_lds[0][0] + tid * 4) = av;
        *reinterpret_cast<float4*>(out_a + (size_t)nt * (VV * VV) + tid * 4) = av;
    }
    __syncthreads();

    const int f = tid;
    float h[VV];
    #pragma unroll
    for (int v = 0; v < VV; ++v) h[v] = 0.0f;
    #pragma unroll 4
    for (int c = 0; c < CC; ++c) {
        float wv = W[c * FF + f];
        #pragma unroll
        for (int v = 0; v < VV; ++v) h[v] = fmaf(x_lds[c][v], wv, h[v]);
    }
    const float bias = b[f];
    #pragma unroll
    for (int v = 0; v < VV; ++v) h[v] += bias;
    float o[VV];
    #pragma unroll
    for (int w = 0; w < VV; ++w) o[w] = 0.0f;
    #pragma unroll
    for (int v = 0; v < VV; ++v) {
        float hv = h[v];
        #pragma unroll
        for (int w = 0; w < VV; ++w) o[w] = fmaf(hv, a_lds[v][w], o[w]);
    }
    float* ob = out + (((size_t)n * FF + f) * TT + t) * VV;
    #pragma unroll
    for (int w = 0; w < VV; w += 4)
        *reinterpret_cast<float4*>(ob + w) = make_float4(o[w], o[w+1], o[w+2], o[w+3]);
}

extern "C" void kernel_launch(void* const* d_in, const int* in_sizes, int n_in,
                              void* d_out, int out_size, void* d_ws, size_t ws_size,
                              hipStream_t stream) {
    const float* x = (const float*)d_in[0];
    const float* a = (const float*)d_in[1];
    const float* W = (const float*)d_in[2];
    const float* b = (const float*)d_in[3];

    float* out   = (float*)d_out;
    float* out_a = out + (size_t)NN * FF * TT * VV;

    const size_t wt_bytes = (size_t)FF * CC * sizeof(_Float16);  // 131072

    if (ws_size >= wt_bytes) {
        _Float16* Wt = (_Float16*)d_ws;
        wt_prep_kernel<<<dim3(CC), dim3(FF), 0, stream>>>(W, Wt);
        sgcn_mfma_kernel<<<dim3(NN * TT), dim3(256), 0, stream>>>(x, a, Wt, b, out, out_a);
    } else {
        sgcn_fused_kernel<<<dim3(NN * TT), dim3(256), 0, stream>>>(x, a, W, b, out, out_a);
    }
}

// Round 5
// 222.635 us; speedup vs baseline: 2.8223x; 1.0945x over previous
//
#include <hip/hip_runtime.h>

// SGCN fused, MFMA v2: TB=4 t per block, swapped GEMM-B (float4 stores),
// f32 a-staging (no sub-word LDS writes).
// out[n,f,t,w] = sum_c W[c,f] * g[c,w] + b[f]*s[w],  g[c,w] = sum_v x[n,c,t,v]*a[n,t,v,w]
// x[128,256,64,32] f32, a[128,64,32,32] f32, W[256,256] f32, b[256] f32
// d_out = out (67,108,864 f32) ++ a (8,388,608 f32);  d_ws = Wt f16 [f][c] (131072 B)

#define NN 128
#define CC 256
#define TT 64
#define VV 32
#define FF 256
#define TB 4
#define AL 33    // a_lds row stride (f32): 33 ≡ 1 mod 32 -> 2-way max on all accesses
#define GL 264   // g_lds row stride (f16): 132 words ≡ 4 mod 32 -> uniform banks for b64/b128

typedef _Float16 half8 __attribute__((ext_vector_type(8)));
typedef _Float16 half4 __attribute__((ext_vector_type(4)));
typedef float floatx4 __attribute__((ext_vector_type(4)));

__global__ __launch_bounds__(256) void wt_prep_kernel(const float* __restrict__ W,
                                                      _Float16* __restrict__ Wt) {
    const int c = blockIdx.x;
    const int f = threadIdx.x;
    Wt[f * CC + c] = (_Float16)W[c * FF + f];
}

__global__ __launch_bounds__(256) void sgcn_mfma2_kernel(
    const float* __restrict__ x, const float* __restrict__ a,
    const _Float16* __restrict__ Wt, const float* __restrict__ b,
    float* __restrict__ out, float* __restrict__ out_a)
{
    __shared__ float    a_lds[TB][VV][AL];   // a[v][w] f32, un-transposed
    __shared__ _Float16 g_lds[VV][GL];       // g^T [w][c] f16 (one t at a time)
    __shared__ float    s_lds[TB][VV];       // s[w] = sum_v a[v][w]

    const int tid  = threadIdx.x;
    const int lane = tid & 63;
    const int wv   = tid >> 6;       // wave 0..3
    const int l15  = lane & 15;
    const int lg   = lane >> 4;      // 0..3
    const int blk  = blockIdx.x;
    const int n    = blk >> 4;       // 16 t-groups per n
    const int t0   = (blk & 15) * TB;

    // ---- phase 0: load a tile (TB t's), mirror to out tail, stage f32 into LDS
    {
        const int v  = tid >> 3;
        const int w0 = (tid & 7) * 4;
        #pragma unroll
        for (int it = 0; it < TB; ++it) {
            const size_t off = ((size_t)(n * TT + t0 + it)) * (VV * VV) + tid * 4;
            float4 av = *reinterpret_cast<const float4*>(a + off);
            *reinterpret_cast<float4*>(out_a + off) = av;
            a_lds[it][v][w0 + 0] = av.x;   // 4 scalar b32 writes: no alignment
            a_lds[it][v][w0 + 1] = av.y;   // constraint, <=3-way banks
            a_lds[it][v][w0 + 2] = av.z;
            a_lds[it][v][w0 + 3] = av.w;
        }
    }

    // ---- prologue: x A-frags for it=0 (in flight under the barrier)
    float4 xf[8];                     // [ci][2]
    #pragma unroll
    for (int ci = 0; ci < 4; ++ci) {
        const int c = (wv * 4 + ci) * 16 + l15;
        const float* xp = x + (((size_t)n * CC + c) * TT + t0) * VV + 8 * lg;
        xf[ci * 2 + 0] = *reinterpret_cast<const float4*>(xp);
        xf[ci * 2 + 1] = *reinterpret_cast<const float4*>(xp + 4);
    }

    // bias values per lane (col f = 16*(4wv+fi)+l15), hoisted
    float bv[4];
    #pragma unroll
    for (int fi = 0; fi < 4; ++fi) bv[fi] = b[16 * (wv * 4 + fi) + l15];

    __syncthreads();                  // a_lds ready

    // ---- column sums s[it][w] (threads 0..127; read bank-free: 33 ≡ 1 mod 32)
    if (tid < TB * VV) {
        const int it = tid >> 5, w = tid & 31;
        float ss = 0.0f;
        #pragma unroll
        for (int v = 0; v < VV; ++v) ss += a_lds[it][v][w];
        s_lds[it][w] = ss;
    }

    #pragma unroll
    for (int it = 0; it < TB; ++it) {
        // ---- B-frags of a: B[v, w=16wt+l15], k-chunk 8lg (8 scalar reads + cvt)
        half8 bA0, bA1;
        #pragma unroll
        for (int j = 0; j < 8; ++j) {
            bA0[j] = (_Float16)a_lds[it][8 * lg + j][l15];
            bA1[j] = (_Float16)a_lds[it][8 * lg + j][16 + l15];
        }

        // convert prefetched x to f16 A-frags
        half8 af[4];
        #pragma unroll
        for (int ci = 0; ci < 4; ++ci) {
            float4 x0 = xf[ci * 2 + 0], x1 = xf[ci * 2 + 1];
            af[ci][0] = (_Float16)x0.x; af[ci][1] = (_Float16)x0.y;
            af[ci][2] = (_Float16)x0.z; af[ci][3] = (_Float16)x0.w;
            af[ci][4] = (_Float16)x1.x; af[ci][5] = (_Float16)x1.y;
            af[ci][6] = (_Float16)x1.z; af[ci][7] = (_Float16)x1.w;
        }

        // issue x loads for next t (hide under phase 2 + barrier)
        if (it + 1 < TB) {
            #pragma unroll
            for (int ci = 0; ci < 4; ++ci) {
                const int c = (wv * 4 + ci) * 16 + l15;
                const float* xp = x + (((size_t)n * CC + c) * TT + (t0 + it + 1)) * VV + 8 * lg;
                xf[ci * 2 + 0] = *reinterpret_cast<const float4*>(xp);
                xf[ci * 2 + 1] = *reinterpret_cast<const float4*>(xp + 4);
            }
        }

        // ---- phase 1: g[c,w] = sum_v x*a; write g^T rows (b64, uniform banks)
        #pragma unroll
        for (int ci = 0; ci < 4; ++ci) {
            const int ct = wv * 4 + ci;
            #pragma unroll
            for (int wt = 0; wt < 2; ++wt) {
                floatx4 acc = {0.f, 0.f, 0.f, 0.f};
                acc = __builtin_amdgcn_mfma_f32_16x16x32_f16(af[ci], wt ? bA1 : bA0, acc, 0, 0, 0);
                half4 gh;
                gh[0] = (_Float16)acc[0]; gh[1] = (_Float16)acc[1];
                gh[2] = (_Float16)acc[2]; gh[3] = (_Float16)acc[3];
                *reinterpret_cast<half4*>(&g_lds[16 * wt + l15][ct * 16 + 4 * lg]) = gh;
            }
        }
        __syncthreads();              // g ready

        // ---- phase 2: D[w,f] = g^T · Wt   (A = g-frag rows w, B = Wt cols f)
        floatx4 acc2[8];              // [fi][mt]
        #pragma unroll
        for (int q = 0; q < 8; ++q) acc2[q] = (floatx4){0.f, 0.f, 0.f, 0.f};

        #pragma unroll
        for (int ks = 0; ks < 8; ++ks) {
            half8 ga0 = *reinterpret_cast<const half8*>(&g_lds[l15][32 * ks + 8 * lg]);
            half8 ga1 = *reinterpret_cast<const half8*>(&g_lds[16 + l15][32 * ks + 8 * lg]);
            #pragma unroll
            for (int fi = 0; fi < 4; ++fi) {
                const int ft = wv * 4 + fi;
                half8 wb = *reinterpret_cast<const half8*>(
                    Wt + (size_t)(16 * ft + l15) * CC + 32 * ks + 8 * lg);
                acc2[fi * 2 + 0] = __builtin_amdgcn_mfma_f32_16x16x32_f16(ga0, wb, acc2[fi * 2 + 0], 0, 0, 0);
                acc2[fi * 2 + 1] = __builtin_amdgcn_mfma_f32_16x16x32_f16(ga1, wb, acc2[fi * 2 + 1], 0, 0, 0);
            }
        }

        // ---- epilogue: out[n, f, t, w0..w0+3] = acc + b[f]*s[w]  (float4 stores)
        #pragma unroll
        for (int fi = 0; fi < 4; ++fi) {
            const int f = 16 * (wv * 4 + fi) + l15;
            float* ob = out + (((size_t)n * FF + f) * TT + (t0 + it)) * VV;
            #pragma unroll
            for (int mt = 0; mt < 2; ++mt) {
                const int w0 = 16 * mt + 4 * lg;
                float4 sv = *reinterpret_cast<const float4*>(&s_lds[it][w0]);
                float4 o;
                o.x = acc2[fi * 2 + mt][0] + bv[fi] * sv.x;
                o.y = acc2[fi * 2 + mt][1] + bv[fi] * sv.y;
                o.z = acc2[fi * 2 + mt][2] + bv[fi] * sv.z;
                o.w = acc2[fi * 2 + mt][3] + bv[fi] * sv.w;
                *reinterpret_cast<float4*>(ob + w0) = o;
            }
        }
        if (it + 1 < TB) __syncthreads();   // g consumed; safe to overwrite
    }
}

// ---- fallback (verified round-3 scalar kernel): used only if ws too small
__global__ __launch_bounds__(256) void sgcn_fused_kernel(
    const float* __restrict__ x, const float* __restrict__ a,
    const float* __restrict__ W, const float* __restrict__ b,
    float* __restrict__ out, float* __restrict__ out_a)
{
    __shared__ float x_lds[CC][VV];
    __shared__ float a_lds[VV][VV];
    const int tid = threadIdx.x;
    const int nt  = blockIdx.x;
    const int n   = nt >> 6;
    const int t   = nt & 63;
    const float* xb = x + (size_t)n * CC * TT * VV + (size_t)t * VV;
    #pragma unroll
    for (int k = 0; k < 8; ++k) {
        int e = tid * 4 + k * 1024;
        int c = e >> 5, v = e & 31;
        float4 val = *reinterpret_cast<const float4*>(xb + (size_t)c * (TT * VV) + v);
        *reinterpret_cast<float4*>(&x_lds[c][v]) = val;
    }
    {
        const float* ab = a + (size_t)nt * (VV * VV);
        float4 av = *reinterpret_cast<const float4*>(ab + tid * 4);
        *reinterpret_cast<float4*>(&a_lds[0][0] + tid * 4) = av;
        *reinterpret_cast<float4*>(out_a + (size_t)nt * (VV * VV) + tid * 4) = av;
    }
    __syncthreads();
    const int f = tid;
    float h[VV];
    #pragma unroll
    for (int v = 0; v < VV; ++v) h[v] = 0.0f;
    #pragma unroll 4
    for (int c = 0; c < CC; ++c) {
        float wv = W[c * FF + f];
        #pragma unroll
        for (int v = 0; v < VV; ++v) h[v] = fmaf(x_lds[c][v], wv, h[v]);
    }
    const float bias = b[f];
    #pragma unroll
    for (int v = 0; v < VV; ++v) h[v] += bias;
    float o[VV];
    #pragma unroll
    for (int w = 0; w < VV; ++w) o[w] = 0.0f;
    #pragma unroll
    for (int v = 0; v < VV; ++v) {
        float hv = h[v];
        #pragma unroll
        for (int w = 0; w < VV; ++w) o[w] = fmaf(hv, a_lds[v][w], o[w]);
    }
    float* ob = out + (((size_t)n * FF + f) * TT + t) * VV;
    #pragma unroll
    for (int w = 0; w < VV; w += 4)
        *reinterpret_cast<float4*>(ob + w) = make_float4(o[w], o[w+1], o[w+2], o[w+3]);
}

extern "C" void kernel_launch(void* const* d_in, const int* in_sizes, int n_in,
                              void* d_out, int out_size, void* d_ws, size_t ws_size,
                              hipStream_t stream) {
    const float* x = (const float*)d_in[0];
    const float* a = (const float*)d_in[1];
    const float* W = (const float*)d_in[2];
    const float* b = (const float*)d_in[3];

    float* out   = (float*)d_out;
    float* out_a = out + (size_t)NN * FF * TT * VV;

    const size_t wt_bytes = (size_t)FF * CC * sizeof(_Float16);  // 131072

    if (ws_size >= wt_bytes) {
        _Float16* Wt = (_Float16*)d_ws;
        wt_prep_kernel<<<dim3(CC), dim3(FF), 0, stream>>>(W, Wt);
        sgcn_mfma2_kernel<<<dim3(NN * (TT / TB)), dim3(256), 0, stream>>>(x, a, Wt, b, out, out_a);
    } else {
        sgcn_fused_kernel<<<dim3(NN * TT), dim3(256), 0, stream>>>(x, a, W, b, out, out_a);
    }
}

// Round 6
// 162.093 us; speedup vs baseline: 3.8764x; 1.3735x over previous
//
#include <hip/hip_runtime.h>

// SGCN fused, MFMA v3: Wt hoisted to registers (32 b128 in flight), batched x loads,
// XOR-swizzled g_lds (bank-conflict-free b128), g double-buffer (1 barrier per t),
// TB=2, __launch_bounds__(256,2) to unlock VGPR budget for MLP.
// out[n,f,t,w] = sum_c W[c,f]*g[c,w] + b[f]*s[w],  g[c,w] = sum_v x[n,c,t,v]*a[n,t,v,w]
// x[128,256,64,32] f32, a[128,64,32,32] f32, W[256,256] f32, b[256] f32
// d_out = out (67,108,864 f32) ++ a (8,388,608 f32);  d_ws = Wt f16 [f][c] (131072 B)

#define NN 128
#define CC 256
#define TT 64
#define VV 32
#define FF 256
#define TB 2
#define AL 33    // a_lds f32 row stride: ≡1 mod 32 -> ≤2-way on all accesses

typedef _Float16 half8 __attribute__((ext_vector_type(8)));
typedef _Float16 half4 __attribute__((ext_vector_type(4)));
typedef float floatx4 __attribute__((ext_vector_type(4)));

__global__ __launch_bounds__(256) void wt_prep_kernel(const float* __restrict__ W,
                                                      _Float16* __restrict__ Wt) {
    const int c = blockIdx.x;
    const int f = threadIdx.x;
    Wt[f * CC + c] = (_Float16)W[c * FF + f];
}

__global__ __launch_bounds__(256, 2) void sgcn_mfma3_kernel(
    const float* __restrict__ x, const float* __restrict__ a,
    const _Float16* __restrict__ Wt, const float* __restrict__ b,
    float* __restrict__ out, float* __restrict__ out_a)
{
    __shared__ float    a_lds[TB][VV][AL];      // 8448 B, f32 un-transposed
    __shared__ _Float16 g_lds[2][VV][256];      // 32 KB, row=512B, XOR-swizzled
    __shared__ float    s_lds[TB][VV];          // 256 B

    const int tid  = threadIdx.x;
    const int lane = tid & 63;
    const int wv   = tid >> 6;       // wave 0..3
    const int l15  = lane & 15;
    const int lg   = lane >> 4;      // 0..3
    const int blk  = blockIdx.x;
    const int n    = blk >> 5;       // TT/TB = 32 t-groups per n
    const int t0   = (blk & 31) * TB;

    // ---- hoist: this wave's 32 Wt fragments (f-tiles 4wv..4wv+3, all ks).
    // Issued first so their L2 latency hides under a-staging + barrier.
    half8 wb[32];
    #pragma unroll
    for (int fi = 0; fi < 4; ++fi) {
        const int f = 16 * (wv * 4 + fi) + l15;
        const _Float16* wp = Wt + (size_t)f * CC + 8 * lg;
        #pragma unroll
        for (int ks = 0; ks < 8; ++ks)
            wb[fi * 8 + ks] = *reinterpret_cast<const half8*>(wp + 32 * ks);
    }

    // ---- phase 0: load a (TB t's), mirror to out tail, stage f32 into LDS
    {
        const int v  = tid >> 3;
        const int w0 = (tid & 7) * 4;
        #pragma unroll
        for (int it = 0; it < TB; ++it) {
            const size_t off = ((size_t)(n * TT + t0 + it)) * (VV * VV) + tid * 4;
            float4 av = *reinterpret_cast<const float4*>(a + off);
            *reinterpret_cast<float4*>(out_a + off) = av;
            a_lds[it][v][w0 + 0] = av.x;
            a_lds[it][v][w0 + 1] = av.y;
            a_lds[it][v][w0 + 2] = av.z;
            a_lds[it][v][w0 + 3] = av.w;
        }
    }

    float bv[4];
    #pragma unroll
    for (int fi = 0; fi < 4; ++fi) bv[fi] = b[16 * (wv * 4 + fi) + l15];

    __syncthreads();                  // a_lds ready

    // ---- column sums s[it][w] (wave 0; consumed after the it=0 g-barrier)
    if (tid < TB * VV) {
        const int it = tid >> 5, w = tid & 31;
        float ss = 0.0f;
        #pragma unroll
        for (int v = 0; v < VV; ++v) ss += a_lds[it][v][w];
        s_lds[it][w] = ss;
    }

    char* gbase = (char*)&g_lds[0][0][0];

    #pragma unroll
    for (int it = 0; it < TB; ++it) {
        const int buf = (it & 1) * (VV * 256 * 2);   // byte offset of g buffer

        // ---- batched x loads (8 independent b128, all in flight)
        float4 xf[8];
        #pragma unroll
        for (int ci = 0; ci < 4; ++ci) {
            const int c = (wv * 4 + ci) * 16 + l15;
            const float* xp = x + (((size_t)n * CC + c) * TT + (t0 + it)) * VV + 8 * lg;
            xf[ci * 2 + 0] = *reinterpret_cast<const float4*>(xp);
            xf[ci * 2 + 1] = *reinterpret_cast<const float4*>(xp + 4);
        }

        // ---- B-frags of a: col w=16wt+l15, k=v=8lg+j (scalar LDS reads, <=2-way)
        half8 bA0, bA1;
        #pragma unroll
        for (int j = 0; j < 8; ++j) {
            bA0[j] = (_Float16)a_lds[it][8 * lg + j][l15];
            bA1[j] = (_Float16)a_lds[it][8 * lg + j][16 + l15];
        }

        // ---- A-frags from x
        half8 af[4];
        #pragma unroll
        for (int ci = 0; ci < 4; ++ci) {
            float4 x0 = xf[ci * 2 + 0], x1 = xf[ci * 2 + 1];
            af[ci][0] = (_Float16)x0.x; af[ci][1] = (_Float16)x0.y;
            af[ci][2] = (_Float16)x0.z; af[ci][3] = (_Float16)x0.w;
            af[ci][4] = (_Float16)x1.x; af[ci][5] = (_Float16)x1.y;
            af[ci][6] = (_Float16)x1.z; af[ci][7] = (_Float16)x1.w;
        }

        // ---- GEMM-A: g[c,w]; write g^T rows with XOR swizzle (byte ^= (row&7)<<4)
        #pragma unroll
        for (int ci = 0; ci < 4; ++ci) {
            const int ct = wv * 4 + ci;
            #pragma unroll
            for (int wt = 0; wt < 2; ++wt) {
                floatx4 acc = {0.f, 0.f, 0.f, 0.f};
                acc = __builtin_amdgcn_mfma_f32_16x16x32_f16(af[ci], wt ? bA1 : bA0, acc, 0, 0, 0);
                half4 gh;
                gh[0] = (_Float16)acc[0]; gh[1] = (_Float16)acc[1];
                gh[2] = (_Float16)acc[2]; gh[3] = (_Float16)acc[3];
                const int row = 16 * wt + l15;
                const int col_b = (ct * 16 + 4 * lg) * 2;            // 8B-aligned
                *reinterpret_cast<half4*>(gbase + buf + row * 512 +
                                          (col_b ^ ((row & 7) << 4))) = gh;
            }
        }
        __syncthreads();              // g[buf] ready (it=0: also s_lds ready)

        // ---- GEMM-B: D[w,f] = g^T · Wt, Wt from registers (pure LDS+MFMA)
        floatx4 acc2[8];
        #pragma unroll
        for (int q = 0; q < 8; ++q) acc2[q] = (floatx4){0.f, 0.f, 0.f, 0.f};

        #pragma unroll
        for (int ks = 0; ks < 8; ++ks) {
            const int r0 = l15, r1 = 16 + l15;
            const int cb = (32 * ks + 8 * lg) * 2;                   // 16B-aligned
            half8 ga0 = *reinterpret_cast<const half8*>(gbase + buf + r0 * 512 +
                                                        (cb ^ ((r0 & 7) << 4)));
            half8 ga1 = *reinterpret_cast<const half8*>(gbase + buf + r1 * 512 +
                                                        (cb ^ ((r1 & 7) << 4)));
            #pragma unroll
            for (int fi = 0; fi < 4; ++fi) {
                acc2[fi * 2 + 0] = __builtin_amdgcn_mfma_f32_16x16x32_f16(ga0, wb[fi * 8 + ks], acc2[fi * 2 + 0], 0, 0, 0);
                acc2[fi * 2 + 1] = __builtin_amdgcn_mfma_f32_16x16x32_f16(ga1, wb[fi * 8 + ks], acc2[fi * 2 + 1], 0, 0, 0);
            }
        }

        // ---- epilogue: out[n,f,t,w0..3] = acc + b[f]*s[w]  (float4 stores)
        #pragma unroll
        for (int fi = 0; fi < 4; ++fi) {
            const int f = 16 * (wv * 4 + fi) + l15;
            float* ob = out + (((size_t)n * FF + f) * TT + (t0 + it)) * VV;
            #pragma unroll
            for (int mt = 0; mt < 2; ++mt) {
                const int w0 = 16 * mt + 4 * lg;
                float4 sv = *reinterpret_cast<const float4*>(&s_lds[it][w0]);
                float4 o;
                o.x = acc2[fi * 2 + mt][0] + bv[fi] * sv.x;
                o.y = acc2[fi * 2 + mt][1] + bv[fi] * sv.y;
                o.z = acc2[fi * 2 + mt][2] + bv[fi] * sv.z;
                o.w = acc2[fi * 2 + mt][3] + bv[fi] * sv.w;
                *reinterpret_cast<float4*>(ob + w0) = o;
            }
        }
        // no trailing barrier: next it uses the other g buffer; its own barrier
        // cannot be passed until every wave finished reading this buffer.
    }
}

// ---- fallback (verified round-3 scalar kernel): used only if ws too small
__global__ __launch_bounds__(256) void sgcn_fused_kernel(
    const float* __restrict__ x, const float* __restrict__ a,
    const float* __restrict__ W, const float* __restrict__ b,
    float* __restrict__ out, float* __restrict__ out_a)
{
    __shared__ float x_lds[CC][VV];
    __shared__ float a_lds[VV][VV];
    const int tid = threadIdx.x;
    const int nt  = blockIdx.x;
    const int n   = nt >> 6;
    const int t   = nt & 63;
    const float* xb = x + (size_t)n * CC * TT * VV + (size_t)t * VV;
    #pragma unroll
    for (int k = 0; k < 8; ++k) {
        int e = tid * 4 + k * 1024;
        int c = e >> 5, v = e & 31;
        float4 val = *reinterpret_cast<const float4*>(xb + (size_t)c * (TT * VV) + v);
        *reinterpret_cast<float4*>(&x_lds[c][v]) = val;
    }
    {
        const float* ab = a + (size_t)nt * (VV * VV);
        float4 av = *reinterpret_cast<const float4*>(ab + tid * 4);
        *reinterpret_cast<float4*>(&a_lds[0][0] + tid * 4) = av;
        *reinterpret_cast<float4*>(out_a + (size_t)nt * (VV * VV) + tid * 4) = av;
    }
    __syncthreads();
    const int f = tid;
    float h[VV];
    #pragma unroll
    for (int v = 0; v < VV; ++v) h[v] = 0.0f;
    #pragma unroll 4
    for (int c = 0; c < CC; ++c) {
        float wv = W[c * FF + f];
        #pragma unroll
        for (int v = 0; v < VV; ++v) h[v] = fmaf(x_lds[c][v], wv, h[v]);
    }
    const float bias = b[f];
    #pragma unroll
    for (int v = 0; v < VV; ++v) h[v] += bias;
    float o[VV];
    #pragma unroll
    for (int w = 0; w < VV; ++w) o[w] = 0.0f;
    #pragma unroll
    for (int v = 0; v < VV; ++v) {
        float hv = h[v];
        #pragma unroll
        for (int w = 0; w < VV; ++w) o[w] = fmaf(hv, a_lds[v][w], o[w]);
    }
    float* ob = out + (((size_t)n * FF + f) * TT + t) * VV;
    #pragma unroll
    for (int w = 0; w < VV; w += 4)
        *reinterpret_cast<float4*>(ob + w) = make_float4(o[w], o[w+1], o[w+2], o[w+3]);
}

extern "C" void kernel_launch(void* const* d_in, const int* in_sizes, int n_in,
                              void* d_out, int out_size, void* d_ws, size_t ws_size,
                              hipStream_t stream) {
    const float* x = (const float*)d_in[0];
    const float* a = (const float*)d_in[1];
    const float* W = (const float*)d_in[2];
    const float* b = (const float*)d_in[3];

    float* out   = (float*)d_out;
    float* out_a = out + (size_t)NN * FF * TT * VV;

    const size_t wt_bytes = (size_t)FF * CC * sizeof(_Float16);  // 131072

    if (ws_size >= wt_bytes) {
        _Float16* Wt = (_Float16*)d_ws;
        wt_prep_kernel<<<dim3(CC), dim3(FF), 0, stream>>>(W, Wt);
        sgcn_mfma3_kernel<<<dim3(NN * (TT / TB)), dim3(256), 0, stream>>>(x, a, Wt, b, out, out_a);
    } else {
        sgcn_fused_kernel<<<dim3(NN * TT), dim3(256), 0, stream>>>(x, a, W, b, out, out_a);
    }
}